// Round 9
// baseline (479.507 us; speedup 1.0000x reference)
//
#include <hip/hip_runtime.h>
#include <hip/hip_bf16.h>
#include <math.h>

typedef unsigned short u16;
typedef __attribute__((ext_vector_type(8))) short s16x8;
typedef __attribute__((ext_vector_type(4))) float f32x4;

#define SCALE 0.083333333333333329f   // 1/sqrt(144)
#define SOFTCAP_INV 0.02f

__device__ __forceinline__ u16 f2bf(float f) {
    unsigned u = __float_as_uint(f);
    unsigned r = 0x7fffu + ((u >> 16) & 1u);
    return (u16)((u + r) >> 16);
}

__device__ __forceinline__ float fast_tanh(float x) {
    float e = __expf(2.0f * x);
    return 1.0f - 2.0f / (e + 1.0f);
}

// ---------------- cast fp32 -> bf16 (vectorized) ----------------
__global__ __launch_bounds__(256) void cast_kernel(const float* __restrict__ in,
                                                   u16* __restrict__ out) {
    size_t i = ((size_t)blockIdx.x * 256 + threadIdx.x) * 4;
    float4 v = *(const float4*)(in + i);
    ushort4 o;
    o.x = f2bf(v.x); o.y = f2bf(v.y); o.z = f2bf(v.z); o.w = f2bf(v.w);
    *(ushort4*)(out + i) = o;
}

// ---------------- rope cos/sin table (float2 interleaved) ----------------
__global__ __launch_bounds__(256) void rope_table_kernel(float2* __restrict__ csT) {
    int idx = blockIdx.x * 256 + threadIdx.x;   // L*64
    int i = idx & 63, pos = idx >> 6;
    float inv = __expf(-((float)i / 64.0f) * 9.210340371976184f); // 10000^(-i/64)
    float ang = (float)pos * inv;
    csT[idx] = make_float2(cosf(ang), sinf(ang));
}

// ---------------- V transpose: Vraw[L][2048] bf16 -> Vt[2048][L] bf16 ----------------
__global__ __launch_bounds__(256) void vtrans_kernel(const u16* __restrict__ Vraw,
                                                     u16* __restrict__ Vt) {
    __shared__ u16 tile[32][33];
    int bc = (blockIdx.x & 63) << 5;    // col within V block (0..2047)
    int bl = (blockIdx.x >> 6) << 5;    // row (l) tile
    int x = threadIdx.x & 31, y = threadIdx.x >> 5;
    #pragma unroll
    for (int yy = y; yy < 32; yy += 8)
        tile[yy][x] = Vraw[(size_t)(bl + yy) * 2048 + bc + x];
    __syncthreads();
    #pragma unroll
    for (int yy = y; yy < 32; yy += 8)
        Vt[(size_t)(bc + yy) * 2048 + bl + x] = tile[x][yy];
}

// ============ 256x256 8-wave 4-phase GEMM main loop (4M x 2N wave layout) ============
// BK=64. 512 thr = 8 waves: wm=wave>>1 (64 rows), wn=wave&1 (128 cols); acc[4][8].
// LDS 128KB = 2 bufs x (A 32KB + B 32KB), XOR swizzle (row&7)<<4 via pre-swizzled
// global source + swizzled ds_read.  Phase quadrants (kk, n-half):
//   P0(cb0,n0-3): 8 ds_read, 16 MFMA   P1(cb0,n4-7): 4 ds_read, 16 MFMA
//   P2(cb1,n0-3): 8 ds_read, 16 MFMA   P3(cb1,n4-7): 4 ds_read, 16 MFMA
// Stage t+1 spread: P0:{A0,A1} P1:{A2,A3} P2:{B0,B2} P3:{B1,B3}.
// Derived waits (age-order): vmcnt(4) before P0 (drains A*(t),B0,B2(t); keeps
// B1,B3(t)+A0,A1(t+1)); vmcnt(4) before P1 (drains B1,B3(t)); none at P2/P3.
// Last tile: vmcnt(2)/vmcnt(0).  Prologue order: A0 A1 A2 A3 B0 B2 B1 B3.
#define STAGE_A(buf, ktt, l)                                                            \
    __builtin_amdgcn_global_load_lds(                                                   \
        (const __attribute__((address_space(1))) unsigned int*)(aSrc + (size_t)(ktt) * 64 + (size_t)(l) * 64 * K), \
        (__attribute__((address_space(3))) unsigned int*)(&lds[buf][0][(l) * 4096 + ldsoff]), 16, 0, 0)
#define STAGE_B(buf, ktt, l)                                                            \
    __builtin_amdgcn_global_load_lds(                                                   \
        (const __attribute__((address_space(1))) unsigned int*)(bSrc + (size_t)(ktt) * 64 + (size_t)(l) * 64 * K), \
        (__attribute__((address_space(3))) unsigned int*)(&lds[buf][1][(l) * 4096 + ldsoff]), 16, 0, 0)

__device__ __forceinline__ void gemm256_loop(const u16* __restrict__ A,
                                             const u16* __restrict__ B,
                                             int K, int kbeg, int nt,
                                             int bm, int bn,
                                             u16 (&lds)[2][2][16384],
                                             f32x4 (&acc)[4][8]) {
    int t = threadIdx.x;
    int lane = t & 63, wave = t >> 6;
    int wm = wave >> 1, wn = wave & 1;
    int fr = lane & 15, fq = lane >> 4;
    int sw = (fr & 7) << 4;

    int srow = wave * 8 + (lane >> 3);
    int scb = ((lane & 7) * 16) ^ (((lane >> 3) & 7) << 4);   // pre-swizzled src col byte
    const u16* aSrc = A + (size_t)(bm * 256 + srow) * K + kbeg + (scb >> 1);
    const u16* bSrc = B + (size_t)(bn * 256 + srow) * K + kbeg + (scb >> 1);
    int ldsoff = wave * 512;   // elements

    #pragma unroll
    for (int m = 0; m < 4; m++)
        #pragma unroll
        for (int n = 0; n < 8; n++)
            acc[m][n] = (f32x4){0.f, 0.f, 0.f, 0.f};

    // prologue: tile 0 in age order A0 A1 A2 A3 B0 B2 B1 B3
    STAGE_A(0, 0, 0); STAGE_A(0, 0, 1); STAGE_A(0, 0, 2); STAGE_A(0, 0, 3);
    STAGE_B(0, 0, 0); STAGE_B(0, 0, 2); STAGE_B(0, 0, 1); STAGE_B(0, 0, 3);

    for (int it = 0; it < nt; ++it) {
        int cur = it & 1, nxt = cur ^ 1;
        bool more = (it + 1 < nt);
        const char* Ab = (const char*)&lds[cur][0][0];
        const char* Bb = (const char*)&lds[cur][1][0];
        int cb0 = (fq * 16) ^ sw;
        int cb1 = (64 + fq * 16) ^ sw;

        // ---- phase 0: (cb0, n0-3) ----
        if (more) {
            STAGE_A(nxt, it + 1, 0); STAGE_A(nxt, it + 1, 1);
            __builtin_amdgcn_sched_barrier(0);
            asm volatile("s_waitcnt vmcnt(4)" ::: "memory");
        } else {
            asm volatile("s_waitcnt vmcnt(2)" ::: "memory");
        }
        __builtin_amdgcn_s_barrier();
        s16x8 a0[4], b0[4];
        #pragma unroll
        for (int m = 0; m < 4; ++m)
            a0[m] = *(const s16x8*)(Ab + (wm * 64 + m * 16 + fr) * 128 + cb0);
        #pragma unroll
        for (int n = 0; n < 4; ++n)
            b0[n] = *(const s16x8*)(Bb + (wn * 128 + n * 16 + fr) * 128 + cb0);
        __builtin_amdgcn_s_setprio(1);
        #pragma unroll
        for (int m = 0; m < 4; ++m)
            #pragma unroll
            for (int n = 0; n < 4; ++n)
                acc[m][n] = __builtin_amdgcn_mfma_f32_16x16x32_bf16(a0[m], b0[n], acc[m][n], 0, 0, 0);
        __builtin_amdgcn_s_setprio(0);
        __builtin_amdgcn_s_barrier();

        // ---- phase 1: (cb0, n4-7) ----
        if (more) {
            STAGE_A(nxt, it + 1, 2); STAGE_A(nxt, it + 1, 3);
            __builtin_amdgcn_sched_barrier(0);
            asm volatile("s_waitcnt vmcnt(4)" ::: "memory");
        } else {
            asm volatile("s_waitcnt vmcnt(0)" ::: "memory");
        }
        __builtin_amdgcn_s_barrier();
        s16x8 b1[4];
        #pragma unroll
        for (int n = 0; n < 4; ++n)
            b1[n] = *(const s16x8*)(Bb + (wn * 128 + (4 + n) * 16 + fr) * 128 + cb0);
        __builtin_amdgcn_s_setprio(1);
        #pragma unroll
        for (int m = 0; m < 4; ++m)
            #pragma unroll
            for (int n = 0; n < 4; ++n)
                acc[m][4 + n] = __builtin_amdgcn_mfma_f32_16x16x32_bf16(a0[m], b1[n], acc[m][4 + n], 0, 0, 0);
        __builtin_amdgcn_s_setprio(0);
        __builtin_amdgcn_s_barrier();

        // ---- phase 2: (cb1, n0-3) ---- (data already landed; no wait)
        if (more) { STAGE_B(nxt, it + 1, 0); STAGE_B(nxt, it + 1, 2); }
        s16x8 a2[4], b2[4];
        #pragma unroll
        for (int m = 0; m < 4; ++m)
            a2[m] = *(const s16x8*)(Ab + (wm * 64 + m * 16 + fr) * 128 + cb1);
        #pragma unroll
        for (int n = 0; n < 4; ++n)
            b2[n] = *(const s16x8*)(Bb + (wn * 128 + n * 16 + fr) * 128 + cb1);
        __builtin_amdgcn_s_setprio(1);
        #pragma unroll
        for (int m = 0; m < 4; ++m)
            #pragma unroll
            for (int n = 0; n < 4; ++n)
                acc[m][n] = __builtin_amdgcn_mfma_f32_16x16x32_bf16(a2[m], b2[n], acc[m][n], 0, 0, 0);
        __builtin_amdgcn_s_setprio(0);
        __builtin_amdgcn_s_barrier();

        // ---- phase 3: (cb1, n4-7) ----
        if (more) { STAGE_B(nxt, it + 1, 1); STAGE_B(nxt, it + 1, 3); }
        s16x8 b3[4];
        #pragma unroll
        for (int n = 0; n < 4; ++n)
            b3[n] = *(const s16x8*)(Bb + (wn * 128 + (4 + n) * 16 + fr) * 128 + cb1);
        __builtin_amdgcn_s_setprio(1);
        #pragma unroll
        for (int m = 0; m < 4; ++m)
            #pragma unroll
            for (int n = 0; n < 4; ++n)
                acc[m][4 + n] = __builtin_amdgcn_mfma_f32_16x16x32_bf16(a2[m], b3[n], acc[m][4 + n], 0, 0, 0);
        __builtin_amdgcn_s_setprio(0);
        __builtin_amdgcn_s_barrier();   // end of tile: buf[cur] free for reuse
    }
}

// QKV GEMM with fused RoPE epilogue. M=2048,N=8192,K=4608, grid 256 x 512 thr.
// bn<16 -> Q heads (rope+scale -> Qbuf); bn in [16,24) -> K heads (rope -> Kbuf);
// bn >= 24 -> V (plain bf16 rows -> Vraw).
__global__ __launch_bounds__(512) void gemm256_qkv(const u16* __restrict__ A,
                                                   const u16* __restrict__ B,
                                                   u16* __restrict__ Qb,
                                                   u16* __restrict__ Kb,
                                                   u16* __restrict__ Vraw,
                                                   const float2* __restrict__ csT,
                                                   int K) {
    __shared__ u16 lds[2][2][16384];
    int bid = blockIdx.x;
    int x = bid & 7, j = bid >> 3;
    int bn = x * 4 + (j & 3);     // XCD column-stripe
    int bm = j >> 2;
    f32x4 acc[4][8];
    gemm256_loop(A, B, K, 0, K >> 6, bm, bn, lds, acc);

    int lane = threadIdx.x & 63, wave = threadIdx.x >> 6;
    int wm = wave >> 1, wn = wave & 1;
    int fr = lane & 15, fq = lane >> 4;
    int rowbase = bm * 256 + wm * 64 + fq * 4;

    if (bn < 24) {
        // RoPE: pair (i, i+64) = (acc[m][n], acc[m][n+4]), i = n*16+fr
        #pragma unroll
        for (int m = 0; m < 4; ++m)
            #pragma unroll
            for (int n = 0; n < 4; ++n) {
                int i = n * 16 + fr;
                #pragma unroll
                for (int r = 0; r < 4; ++r) {
                    int pos = rowbase + m * 16 + r;
                    float2 cs = csT[(pos << 6) + i];
                    float t1 = acc[m][n][r], t2 = acc[m][n + 4][r];
                    float o1 = t1 * cs.x - t2 * cs.y;
                    float o2 = t2 * cs.x + t1 * cs.y;
                    if (bn < 16) {
                        int head = bn * 2 + wn;
                        size_t base = (size_t)pos * 4096 + head * 128 + i;
                        Qb[base]      = f2bf(o1 * SCALE);
                        Qb[base + 64] = f2bf(o2 * SCALE);
                    } else {
                        int hk = (bn - 16) * 2 + wn;
                        size_t base = (size_t)pos * 2048 + hk * 128 + i;
                        Kb[base]      = f2bf(o1);
                        Kb[base + 64] = f2bf(o2);
                    }
                }
            }
    } else {
        #pragma unroll
        for (int m = 0; m < 4; ++m)
            #pragma unroll
            for (int n = 0; n < 8; ++n) {
                int colv = (bn - 24) * 256 + wn * 128 + n * 16 + fr;
                #pragma unroll
                for (int r = 0; r < 4; ++r)
                    Vraw[(size_t)(rowbase + m * 16 + r) * 2048 + colv] = f2bf(acc[m][n][r]);
            }
    }
}

// out-proj GEMM: M=2048,N=4608,K=4096, full K, f32 store. grid 144 (8 XCD-chunks of 18).
__global__ __launch_bounds__(512) void gemm256_out(const u16* __restrict__ A,
                                                   const u16* __restrict__ B,
                                                   float* __restrict__ C, int K) {
    __shared__ u16 lds[2][2][16384];
    int bid = blockIdx.x;
    int j = (bid & 7) * 18 + (bid >> 3);
    int bm = j & 7;
    int bn = j >> 3;                       // 0..17
    f32x4 acc[4][8];
    gemm256_loop(A, B, K, 0, K >> 6, bm, bn, lds, acc);

    int lane = threadIdx.x & 63, wave = threadIdx.x >> 6;
    int wm = wave >> 1, wn = wave & 1;
    int fr = lane & 15, fq = lane >> 4;
    #pragma unroll
    for (int m = 0; m < 4; ++m) {
        int row = bm * 256 + wm * 64 + m * 16 + fq * 4;
        #pragma unroll
        for (int n = 0; n < 8; ++n) {
            int col = bn * 256 + wn * 128 + n * 16 + fr;
            #pragma unroll
            for (int r = 0; r < 4; ++r)
                C[(size_t)(row + r) * 4608 + col] = acc[m][n][r];
        }
    }
}

// ---------------- flash attention: 4 waves/block, double-buffered K/V ----------------
// Per kv-tile: stage t+1's 8 loads -> vmcnt(8) (t landed, t+1 in flight) -> barrier ->
// compute t -> barrier.  LDS 72KB -> 2 blocks/CU.
__global__ __launch_bounds__(256) void attn_kernel(const u16* __restrict__ Qb,
                                                   const u16* __restrict__ Kb,
                                                   const u16* __restrict__ Vt,
                                                   u16* __restrict__ Ob) {
    __shared__ u16 Ks[2][64 * 128];   // 2 x 16 KB, swizzled
    __shared__ u16 Vs[2][128 * 64];   // 2 x 16 KB, swizzled
    __shared__ u16 Pst[4 * 1024];     // 2 KB per wave

    int bid = blockIdx.x;
    int hq = bid & 31;
    int qb = 31 - (bid >> 5);       // heavy blocks first
    int g = hq >> 1;
    int t = threadIdx.x;
    int lane = t & 63, wave = t >> 6;
    int fr = lane & 15, fq = lane >> 4;
    int sw = (fr & 7) << 4;
    int qrow0 = qb * 64 + wave * 16;
    u16* Pw = &Pst[wave * 1024];
    int w4 = wave * 4;

    s16x8 qf[4];
    #pragma unroll
    for (int s = 0; s < 4; s++)
        qf[s] = *(const s16x8*)&Qb[(size_t)(qrow0 + fr) * 4096 + hq * 128 + s * 32 + fq * 8];

    f32x4 o[8];
    #pragma unroll
    for (int c = 0; c < 8; c++) o[c] = (f32x4){0.f, 0.f, 0.f, 0.f};
    float mi[4] = {-INFINITY, -INFINITY, -INFINITY, -INFINITY};
    float li[4] = {0.f, 0.f, 0.f, 0.f};

    int nT = qb + 1;

    // prologue: stage tile 0 into buf 0
    #pragma unroll
    for (int i = 0; i < 4; i++) {
        int li_ = w4 + i;
        int rk = li_ * 4 + (lane >> 4);
        int cbk = ((lane & 15) * 16) ^ ((rk & 7) << 4);
        const u16* srcK = Kb + (size_t)rk * 2048 + g * 128 + (cbk >> 1);
        __builtin_amdgcn_global_load_lds(
            (const __attribute__((address_space(1))) unsigned int*)srcK,
            (__attribute__((address_space(3))) unsigned int*)(&Ks[0][li_ * 512]), 16, 0, 0);
        int rv = li_ * 8 + (lane >> 3);
        int cbv = ((lane & 7) * 16) ^ ((rv & 7) << 4);
        const u16* srcV = Vt + (size_t)(g * 128 + rv) * 2048 + (cbv >> 1);
        __builtin_amdgcn_global_load_lds(
            (const __attribute__((address_space(1))) unsigned int*)srcV,
            (__attribute__((address_space(3))) unsigned int*)(&Vs[0][li_ * 512]), 16, 0, 0);
    }

    for (int kt = 0; kt < nT; kt++) {
        int kv0 = kt << 6;
        int cur = kt & 1, nxt = cur ^ 1;
        if (kt + 1 < nT) {
            int kvn = (kt + 1) << 6;
            #pragma unroll
            for (int i = 0; i < 4; i++) {
                int li_ = w4 + i;
                int rk = li_ * 4 + (lane >> 4);
                int cbk = ((lane & 15) * 16) ^ ((rk & 7) << 4);
                const u16* srcK = Kb + (size_t)(kvn + rk) * 2048 + g * 128 + (cbk >> 1);
                __builtin_amdgcn_global_load_lds(
                    (const __attribute__((address_space(1))) unsigned int*)srcK,
                    (__attribute__((address_space(3))) unsigned int*)(&Ks[nxt][li_ * 512]), 16, 0, 0);
                int rv = li_ * 8 + (lane >> 3);
                int cbv = ((lane & 7) * 16) ^ ((rv & 7) << 4);
                const u16* srcV = Vt + (size_t)(g * 128 + rv) * 2048 + kvn + (cbv >> 1);
                __builtin_amdgcn_global_load_lds(
                    (const __attribute__((address_space(1))) unsigned int*)srcV,
                    (__attribute__((address_space(3))) unsigned int*)(&Vs[nxt][li_ * 512]), 16, 0, 0);
            }
            __builtin_amdgcn_sched_barrier(0);
            asm volatile("s_waitcnt vmcnt(8)" ::: "memory");   // tile kt landed; kt+1 in flight
        } else {
            asm volatile("s_waitcnt vmcnt(0)" ::: "memory");
        }
        __builtin_amdgcn_s_barrier();

        if (kv0 <= qrow0 + 15) {
            const u16* Kc = &Ks[cur][0];
            const u16* Vc = &Vs[cur][0];
            f32x4 sf[4];
            #pragma unroll
            for (int j = 0; j < 4; j++) sf[j] = (f32x4){0.f, 0.f, 0.f, 0.f};
            #pragma unroll
            for (int j = 0; j < 4; j++)
                #pragma unroll
                for (int s = 0; s < 4; s++) {
                    s16x8 kf = *(const s16x8*)&Kc[(j * 16 + fr) * 128 + (((s * 64 + fq * 16) ^ sw) >> 1)];
                    sf[j] = __builtin_amdgcn_mfma_f32_16x16x32_bf16(qf[s], kf, sf[j], 0, 0, 0);
                }
            float pmax[4] = {-INFINITY, -INFINITY, -INFINITY, -INFINITY};
            #pragma unroll
            for (int j = 0; j < 4; j++)
                #pragma unroll
                for (int r = 0; r < 4; r++) {
                    float sc = 50.f * fast_tanh(sf[j][r] * SOFTCAP_INV);
                    int colk = kv0 + j * 16 + fr;
                    int rowq = qrow0 + fq * 4 + r;
                    sc = (colk > rowq) ? -INFINITY : sc;
                    sf[j][r] = sc;
                    pmax[r] = fmaxf(pmax[r], sc);
                }
            #pragma unroll
            for (int d = 1; d < 16; d <<= 1)
                #pragma unroll
                for (int r = 0; r < 4; r++)
                    pmax[r] = fmaxf(pmax[r], __shfl_xor(pmax[r], d));
            float al[4], psum[4] = {0.f, 0.f, 0.f, 0.f};
            #pragma unroll
            for (int r = 0; r < 4; r++) {
                float mn = fmaxf(mi[r], pmax[r]);
                al[r] = __expf(mi[r] - mn);
                mi[r] = mn;
            }
            #pragma unroll
            for (int j = 0; j < 4; j++)
                #pragma unroll
                for (int r = 0; r < 4; r++) {
                    float p = __expf(sf[j][r] - mi[r]);
                    sf[j][r] = p;
                    psum[r] += p;
                }
            #pragma unroll
            for (int d = 1; d < 16; d <<= 1)
                #pragma unroll
                for (int r = 0; r < 4; r++)
                    psum[r] += __shfl_xor(psum[r], d);
            #pragma unroll
            for (int r = 0; r < 4; r++)
                li[r] = li[r] * al[r] + psum[r];
            #pragma unroll
            for (int c = 0; c < 8; c++)
                #pragma unroll
                for (int r = 0; r < 4; r++)
                    o[c][r] *= al[r];
            #pragma unroll
            for (int j = 0; j < 4; j++)
                #pragma unroll
                for (int r = 0; r < 4; r++) {
                    int row = fq * 4 + r, col = j * 16 + fr;
                    int byteoff = (row * 128 + col * 2) ^ ((row & 7) << 4);
                    *(u16*)((char*)Pw + byteoff) = f2bf(sf[j][r]);
                }
            #pragma unroll
            for (int s = 0; s < 2; s++) {
                int rbyte = (fr * 128 + s * 64 + fq * 16) ^ sw;
                s16x8 pf = *(const s16x8*)((const char*)Pw + rbyte);
                #pragma unroll
                for (int c = 0; c < 8; c++) {
                    s16x8 vf = *(const s16x8*)&Vc[(c * 16 + fr) * 64 + (((s * 64 + fq * 16) ^ sw) >> 1)];
                    o[c] = __builtin_amdgcn_mfma_f32_16x16x32_bf16(pf, vf, o[c], 0, 0, 0);
                }
            }
        }
        __builtin_amdgcn_s_barrier();   // all waves done reading buf[cur]
    }
    #pragma unroll
    for (int c = 0; c < 8; c++)
        #pragma unroll
        for (int r = 0; r < 4; r++) {
            int rowq = qrow0 + fq * 4 + r;
            Ob[(size_t)rowq * 4096 + hq * 128 + c * 16 + fr] = f2bf(o[c][r] / li[r]);
        }
}

extern "C" void kernel_launch(void* const* d_in, const int* in_sizes, int n_in,
                              void* d_out, int out_size, void* d_ws, size_t ws_size,
                              hipStream_t stream) {
    const float* x  = (const float*)d_in[0];
    // d_in[1] = mask (unused; causal computed directly)
    const float* wq = (const float*)d_in[2];
    const float* wk = (const float*)d_in[3];
    const float* wv = (const float*)d_in[4];
    const float* wo = (const float*)d_in[5];
    float* out = (float*)d_out;

    char* w = (char*)d_ws;
    u16*    xb   = (u16*)(w);                    // 2048*4608 bf16      = 18,874,368
    u16*    wb   = (u16*)(w + 18874368);         // 8192*4608 bf16      = 75,497,472
    u16*    Vraw = (u16*)(w + 94371840);         // 2048*2048 bf16      =  8,388,608
    u16*    Ob   = (u16*)(w + 102760448);        // 2048*4096 bf16      = 16,777,216
    u16*    Qbuf = (u16*)(w + 119537664);        // 2048*4096 bf16      = 16,777,216
    u16*    Kbuf = (u16*)(w + 136314880);        // 2048*2048 bf16      =  8,388,608
    u16*    Vt   = (u16*)(w + 144703488);        // 2048*2048 bf16      =  8,388,608
    float2* csT  = (float2*)(w + 153092096);     // 2048*64 float2      =  1,048,576
                                                 // end 154,140,672

    // rope table + input cast
    rope_table_kernel<<<512, 256, 0, stream>>>(csT);
    cast_kernel<<<9216, 256, 0, stream>>>(x, xb);

    // fused QKV weights: wb rows [0,4096)=wq, [4096,6144)=wk, [6144,8192)=wv
    cast_kernel<<<18432, 256, 0, stream>>>(wq, wb);
    cast_kernel<<<9216, 256, 0, stream>>>(wk, wb + (size_t)4096 * 4608);
    cast_kernel<<<9216, 256, 0, stream>>>(wv, wb + (size_t)6144 * 4608);

    // fused QKV GEMM + RoPE epilogue (writes Qbuf/Kbuf/Vraw directly)
    gemm256_qkv<<<256, 512, 0, stream>>>(xb, wb, Qbuf, Kbuf, Vraw, csT, 4608);

    // V transpose
    vtrans_kernel<<<4096, 256, 0, stream>>>(Vraw, Vt);

    // attention
    attn_kernel<<<1024, 256, 0, stream>>>(Qbuf, Kbuf, Vt, Ob);

    // out = attn @ wo^T (2048 x 4608, K=4096), full K, grid 144
    cast_kernel<<<18432, 256, 0, stream>>>(wo, wb);
    gemm256_out<<<144, 512, 0, stream>>>(Ob, wb, out, 4096);
}